// Round 15
// baseline (220.541 us; speedup 1.0000x reference)
//
#include <hip/hip_runtime.h>
#include <hip/hip_bf16.h>

// Problem: B=2048, DIM=2048, SKETCH=256, SIZE=131072
//   sx = normalize_rows(x @ R); out = 1 - max_row(sx @ buffer^T)

#define BROWS 2048
#define DIM   2048
#define SKDIM 256
#define NBUF  131072

#define NGROUPS 32            // n-chunks (4096 cols each)
#define NT_PER  32            // 128-col n-tiles per block

typedef __attribute__((ext_vector_type(4))) float f32x4;
typedef __attribute__((ext_vector_type(8))) short bf16x8;
typedef __attribute__((ext_vector_type(4))) short bf16x4;

static __device__ inline unsigned short f2bf(float f) {
  unsigned u = __float_as_uint(f);
  unsigned r = u + 0x7FFFu + ((u >> 16) & 1u);  // round-to-nearest-even
  return (unsigned short)(r >> 16);
}

static __device__ inline bf16x8 cvt8(const float* __restrict__ p) {
  f32x4 a = *(const f32x4*)p;
  f32x4 b = *(const f32x4*)(p + 4);
  bf16x8 r;
  r[0] = (short)f2bf(a[0]); r[1] = (short)f2bf(a[1]);
  r[2] = (short)f2bf(a[2]); r[3] = (short)f2bf(a[3]);
  r[4] = (short)f2bf(b[0]); r[5] = (short)f2bf(b[1]);
  r[6] = (short)f2bf(b[2]); r[7] = (short)f2bf(b[3]);
  return r;
}

// K1+K2 fused (now also subsumes transpose_R): blocks 0..31 = gemm_sketch
// staging B directly from R (f32 [k][n]) with in-LDS transpose; blocks
// 32..2079 = conv_buf. The 32 sketch blocks hide under the BW-bound conv.
__launch_bounds__(256)
__global__ void sketch_conv(const float* __restrict__ x, const float* __restrict__ R,
                            unsigned short* __restrict__ sx,
                            const float* __restrict__ bufin, unsigned short* __restrict__ outb) {
  __shared__ unsigned short As[64][72];
  __shared__ unsigned short Bs[256][72];
  __shared__ float ssum[4][64];

  if (blockIdx.x >= 32) {
    // ---- conv path (validated R0-R13) ----
    const int nvec = (NBUF * SKDIM) / 4;
    int stride = 2048 * 256;
    for (int i = (blockIdx.x - 32) * 256 + threadIdx.x; i < nvec; i += stride) {
      f32x4 v = ((const f32x4*)bufin)[i];
      bf16x4 r;
      r[0] = (short)f2bf(v[0]); r[1] = (short)f2bf(v[1]);
      r[2] = (short)f2bf(v[2]); r[3] = (short)f2bf(v[3]);
      ((bf16x4*)outb)[i] = r;
    }
    return;
  }

  // ---- sketch path ----
  const int m0 = blockIdx.x * 64;
  const int tid = threadIdx.x;
  const int w = tid >> 6, l = tid & 63;
  const int lr = l & 15, q = l >> 4;

  f32x4 acc[4][4] = {};

  for (int k0 = 0; k0 < DIM; k0 += 64) {
    // stage A (f32 -> bf16), unchanged
    #pragma unroll
    for (int i = 0; i < 2; ++i) {
      int v = tid + i * 256;
      int r = v >> 3, vc = v & 7;
      *(bf16x8*)&As[r][vc * 8] = cvt8(x + (size_t)(m0 + r) * DIM + k0 + vc * 8);
    }
    // stage B directly from R with transpose: Bs[n][kk] = bf16(R[k0+kk][n]).
    // Thread tid = n; loads coalesced across tid; LDS write stride 144B
    // (8-way conflict, negligible — 32 blocks hidden under conv).
    #pragma unroll 8
    for (int kk = 0; kk < 64; ++kk)
      Bs[tid][kk] = f2bf(R[(size_t)(k0 + kk) * SKDIM + tid]);
    __syncthreads();
    #pragma unroll
    for (int ks = 0; ks < 2; ++ks) {
      int kk = ks * 32 + q * 8;
      bf16x8 a[4], b[4];
      #pragma unroll
      for (int mi = 0; mi < 4; ++mi) a[mi] = *(bf16x8*)&As[mi * 16 + lr][kk];
      #pragma unroll
      for (int ni = 0; ni < 4; ++ni) b[ni] = *(bf16x8*)&Bs[w * 64 + ni * 16 + lr][kk];
      #pragma unroll
      for (int mi = 0; mi < 4; ++mi)
        #pragma unroll
        for (int ni = 0; ni < 4; ++ni)
          acc[mi][ni] = __builtin_amdgcn_mfma_f32_16x16x32_bf16(a[mi], b[ni], acc[mi][ni], 0, 0, 0);
    }
    __syncthreads();
  }

  float ps[4][4];
  #pragma unroll
  for (int mi = 0; mi < 4; ++mi)
    #pragma unroll
    for (int rg = 0; rg < 4; ++rg) {
      float s = acc[mi][0][rg] * acc[mi][0][rg] + acc[mi][1][rg] * acc[mi][1][rg]
              + acc[mi][2][rg] * acc[mi][2][rg] + acc[mi][3][rg] * acc[mi][3][rg];
      #pragma unroll
      for (int m = 1; m < 16; m <<= 1) s += __shfl_xor(s, m);
      ps[mi][rg] = s;
    }
  if (lr == 0) {
    #pragma unroll
    for (int mi = 0; mi < 4; ++mi)
      #pragma unroll
      for (int rg = 0; rg < 4; ++rg)
        ssum[w][mi * 16 + q * 4 + rg] = ps[mi][rg];
  }
  __syncthreads();

  #pragma unroll
  for (int mi = 0; mi < 4; ++mi)
    #pragma unroll
    for (int rg = 0; rg < 4; ++rg) {
      int r = mi * 16 + q * 4 + rg;
      float tot = ssum[0][r] + ssum[1][r] + ssum[2][r] + ssum[3][r];
      float inv = 1.0f / fmaxf(sqrtf(tot), 1e-12f);
      #pragma unroll
      for (int ni = 0; ni < 4; ++ni) {
        float val = acc[mi][ni][rg] * inv;
        sx[(size_t)(m0 + r) * SKDIM + w * 64 + ni * 16 + lr] = f2bf(val);
      }
    }
}

// K3 v14 (frozen, validated R13): A-in-regs, 16x16x32, 4 LDS slots, counted
// vmcnt window protocol, WR=4. 8 waves (4 wr x 2 wc), block 256 rows x
// (32 n-tiles x 128 cols).
__launch_bounds__(512, 2)
__global__ void gemm_sim(const unsigned short* __restrict__ sx,
                         const unsigned short* __restrict__ bufb,
                         float* __restrict__ partial) {
  __shared__ __align__(16) char lb[65536];

  const int gid = blockIdx.x;
  const int logical = (gid & 7) * 32 + (gid >> 3);
  const int mt = logical & 7;        // 0..7 m-tile (256 rows)
  const int nc = logical >> 3;       // 0..31 n-chunk (4096 cols)
  const int m0 = mt * 256;
  const int ncbase = nc * (NT_PER * 128);

  const int tid = threadIdx.x;
  const int w = tid >> 6, l = tid & 63;
  const int wr = w >> 1, wc = w & 1;        // wave grid 4 x 2
  const int lr = l & 15, q = l >> 4;

  const int scol = ((tid & 7) ^ ((tid >> 4) & 7)) * 8;   // elements
  const int off0 = ((q ^ ((lr >> 1) & 7)) << 4);
  const int off1 = off0 ^ 64;
  const int rowoff = (wc * 64 + lr) * 128;

  bf16x8 areg[4][8];
  {
    const unsigned short* abase = sx + (size_t)(m0 + wr * 64 + lr) * SKDIM + q * 8;
    #pragma unroll
    for (int mi = 0; mi < 4; ++mi)
      #pragma unroll
      for (int kc = 0; kc < 8; ++kc)
        areg[mi][kc] = *(const bf16x8*)(abase + mi * 16 * SKDIM + kc * 32);
  }

  f32x4 acc[4][4] = {};
  float rm[4][4];
  #pragma unroll
  for (int mi = 0; mi < 4; ++mi)
    #pragma unroll
    for (int rg = 0; rg < 4; ++rg) rm[mi][rg] = -3.0e38f;

  bf16x8 bfn[4];

#define STAGE(srcb, kpart, slot_) do {                                         \
    const unsigned short* s0_ = (srcb) + (kpart) * 64;                         \
    char* dst_ = lb + (slot_) * 16384 + tid * 16;                              \
    __builtin_amdgcn_global_load_lds(                                          \
        (const __attribute__((address_space(1))) unsigned int*)s0_,            \
        (__attribute__((address_space(3))) unsigned int*)dst_, 16, 0, 0);      \
    __builtin_amdgcn_global_load_lds(                                          \
        (const __attribute__((address_space(1))) unsigned int*)(s0_ + 64 * SKDIM), \
        (__attribute__((address_space(3))) unsigned int*)(dst_ + 8192), 16, 0, 0); \
  } while (0)

#define RDNEXT(slotN)                                                          \
    _Pragma("unroll")                                                          \
    for (int ni = 0; ni < 4; ++ni)                                             \
      bfn[ni] = *(const bf16x8*)(lb + (slotN) * 16384 + rowoff + ni * 2048 + off0);

#define WINDOW(ks, VM, STAGE_STMT, RDNEXT_STMT) do {                           \
    asm volatile("s_waitcnt vmcnt(" #VM ")" ::: "memory");                     \
    asm volatile("s_barrier" ::: "memory");                                    \
    bf16x8 b1[4];                                                              \
    _Pragma("unroll")                                                          \
    for (int ni = 0; ni < 4; ++ni)                                             \
      b1[ni] = *(const bf16x8*)(lb + (ks) * 16384 + rowoff + ni * 2048 + off1); \
    __builtin_amdgcn_s_setprio(1);                                             \
    _Pragma("unroll")                                                          \
    for (int mi = 0; mi < 4; ++mi)                                             \
      _Pragma("unroll")                                                        \
      for (int ni = 0; ni < 4; ++ni)                                           \
        acc[mi][ni] = __builtin_amdgcn_mfma_f32_16x16x32_bf16(areg[mi][(ks) * 2], bfn[ni], acc[mi][ni], 0, 0, 0); \
    __builtin_amdgcn_s_setprio(0);                                             \
    STAGE_STMT;                                                                \
    __builtin_amdgcn_s_setprio(1);                                             \
    _Pragma("unroll")                                                          \
    for (int mi = 0; mi < 4; ++mi)                                             \
      _Pragma("unroll")                                                        \
      for (int ni = 0; ni < 4; ++ni)                                           \
        acc[mi][ni] = __builtin_amdgcn_mfma_f32_16x16x32_bf16(areg[mi][(ks) * 2 + 1], b1[ni], acc[mi][ni], 0, 0, 0); \
    __builtin_amdgcn_s_setprio(0);                                             \
    RDNEXT_STMT;                                                               \
  } while (0)

#define FOLD do {                                                              \
    _Pragma("unroll")                                                          \
    for (int mi = 0; mi < 4; ++mi)                                             \
      _Pragma("unroll")                                                        \
      for (int rg = 0; rg < 4; ++rg) {                                         \
        float v = fmaxf(fmaxf(acc[mi][0][rg], acc[mi][1][rg]),                 \
                        fmaxf(acc[mi][2][rg], acc[mi][3][rg]));                \
        rm[mi][rg] = fmaxf(rm[mi][rg], v);                                     \
        _Pragma("unroll")                                                      \
        for (int ni = 0; ni < 4; ++ni) acc[mi][ni][rg] = 0.0f;                 \
      }                                                                        \
  } while (0)

  const unsigned short* bsrc = bufb + (size_t)(ncbase + (tid >> 3)) * SKDIM + scol;

  STAGE(bsrc, 0, 0);
  STAGE(bsrc, 1, 1);
  STAGE(bsrc, 2, 2);
  asm volatile("s_waitcnt vmcnt(4)" ::: "memory");
  asm volatile("s_barrier" ::: "memory");
  RDNEXT(0);

  for (int nt = 0; nt < NT_PER - 1; ++nt) {
    const unsigned short* bcur = bsrc;
    bsrc += 128 * SKDIM;
    WINDOW(0, 2, STAGE(bcur, 3, 3), RDNEXT(1));
    WINDOW(1, 2, STAGE(bsrc, 0, 0), RDNEXT(2));
    WINDOW(2, 2, STAGE(bsrc, 1, 1), RDNEXT(3));
    WINDOW(3, 2, STAGE(bsrc, 2, 2), RDNEXT(0));
    FOLD;
  }
  {  // tail n-tile
    const unsigned short* bcur = bsrc;
    WINDOW(0, 2, STAGE(bcur, 3, 3), RDNEXT(1));
    WINDOW(1, 2, (void)0, RDNEXT(2));
    WINDOW(2, 0, (void)0, RDNEXT(3));
    WINDOW(3, 0, (void)0, (void)0);
    FOLD;
  }
#undef STAGE
#undef RDNEXT
#undef WINDOW
#undef FOLD

  #pragma unroll
  for (int mi = 0; mi < 4; ++mi)
    #pragma unroll
    for (int rg = 0; rg < 4; ++rg) {
      float v = rm[mi][rg];
      v = fmaxf(v, __shfl_xor(v, 1));
      v = fmaxf(v, __shfl_xor(v, 2));
      v = fmaxf(v, __shfl_xor(v, 4));
      v = fmaxf(v, __shfl_xor(v, 8));
      rm[mi][rg] = v;
    }

  float* rmaxs = (float*)lb;   // reuse staging LDS: [2 wc][256 rows]
  __syncthreads();
  if (lr == 0) {
    #pragma unroll
    for (int mi = 0; mi < 4; ++mi)
      #pragma unroll
      for (int rg = 0; rg < 4; ++rg)
        rmaxs[wc * 256 + wr * 64 + mi * 16 + q * 4 + rg] = rm[mi][rg];
  }
  __syncthreads();
  if (tid < 256) {
    float v = fmaxf(rmaxs[tid], rmaxs[256 + tid]);
    partial[(size_t)(m0 + tid) * NGROUPS + nc] = v;
  }
}

// K4: out[r] = 1 - max over 32 partials. 2 rows per 64-thread block.
__global__ void reduce_max(const float* __restrict__ partial, float* __restrict__ out) {
  const int r = blockIdx.x * 2 + (threadIdx.x >> 5);
  const int c = threadIdx.x & 31;
  float m = partial[(size_t)r * NGROUPS + c];
  #pragma unroll
  for (int s = 1; s < 32; s <<= 1) m = fmaxf(m, __shfl_xor(m, s));
  if (c == 0) out[r] = 1.0f - m;
}

extern "C" void kernel_launch(void* const* d_in, const int* in_sizes, int n_in,
                              void* d_out, int out_size, void* d_ws, size_t ws_size,
                              hipStream_t stream) {
  const float* x   = (const float*)d_in[0];   // [2048, 2048]
  const float* R   = (const float*)d_in[1];   // [2048, 256]
  const float* buf = (const float*)d_in[2];   // [131072, 256]
  float* out = (float*)d_out;                  // [2048]

  char* ws = (char*)d_ws;
  // ws layout: (1MB unused) | buf_bf 64MB | sx_bf 1MB | partial 256KB
  unsigned short* bufb = (unsigned short*)(ws + (1ull << 20));
  unsigned short* sxb  = (unsigned short*)(ws + (1ull << 20) + (64ull << 20));
  float*          part = (float*)         (ws + (1ull << 20) + (64ull << 20) + (1ull << 20));

  sketch_conv<<<dim3(2080), dim3(256), 0, stream>>>(x, R, sxb, buf, bufb);
  gemm_sim<<<dim3(256), dim3(512), 0, stream>>>(sxb, bufb, part);
  reduce_max<<<dim3(BROWS / 2), dim3(64), 0, stream>>>(part, out);
}

// Round 16
// 165.765 us; speedup vs baseline: 1.3304x; 1.3304x over previous
//
#include <hip/hip_runtime.h>
#include <hip/hip_bf16.h>

// Problem: B=2048, DIM=2048, SKETCH=256, SIZE=131072
//   sx = normalize_rows(x @ R); out = 1 - max_row(sx @ buffer^T)
// R15 = exact revert to the R13 configuration (best verified: 166.0 us).

#define BROWS 2048
#define DIM   2048
#define SKDIM 256
#define NBUF  131072

#define NGROUPS 32            // n-chunks (4096 cols each)
#define NT_PER  32            // 128-col n-tiles per block

typedef __attribute__((ext_vector_type(4))) float f32x4;
typedef __attribute__((ext_vector_type(8))) short bf16x8;
typedef __attribute__((ext_vector_type(4))) short bf16x4;

static __device__ inline unsigned short f2bf(float f) {
  unsigned u = __float_as_uint(f);
  unsigned r = u + 0x7FFFu + ((u >> 16) & 1u);  // round-to-nearest-even
  return (unsigned short)(r >> 16);
}

static __device__ inline bf16x8 cvt8(const float* __restrict__ p) {
  f32x4 a = *(const f32x4*)p;
  f32x4 b = *(const f32x4*)(p + 4);
  bf16x8 r;
  r[0] = (short)f2bf(a[0]); r[1] = (short)f2bf(a[1]);
  r[2] = (short)f2bf(a[2]); r[3] = (short)f2bf(a[3]);
  r[4] = (short)f2bf(b[0]); r[5] = (short)f2bf(b[1]);
  r[6] = (short)f2bf(b[2]); r[7] = (short)f2bf(b[3]);
  return r;
}

// K0: RT_bf[n][k] = bf16(R[k][n])   (256 x 2048) — coalesced, ~3 us.
__global__ void transpose_R(const float* __restrict__ R, unsigned short* __restrict__ rt) {
  int idx = blockIdx.x * 256 + threadIdx.x;
  int k = idx >> 8, n = idx & 255;
  rt[n * DIM + k] = f2bf(R[idx]);
}

// K1+K2 fused: blocks 0..31 = gemm_sketch; blocks 32..2079 = conv_buf.
__launch_bounds__(256)
__global__ void sketch_conv(const float* __restrict__ x, const unsigned short* __restrict__ rt,
                            unsigned short* __restrict__ sx,
                            const float* __restrict__ bufin, unsigned short* __restrict__ outb) {
  __shared__ unsigned short As[64][72];
  __shared__ unsigned short Bs[256][72];
  __shared__ float ssum[4][64];

  if (blockIdx.x >= 32) {
    // ---- conv path (validated R0-R13) ----
    const int nvec = (NBUF * SKDIM) / 4;
    int stride = 2048 * 256;
    for (int i = (blockIdx.x - 32) * 256 + threadIdx.x; i < nvec; i += stride) {
      f32x4 v = ((const f32x4*)bufin)[i];
      bf16x4 r;
      r[0] = (short)f2bf(v[0]); r[1] = (short)f2bf(v[1]);
      r[2] = (short)f2bf(v[2]); r[3] = (short)f2bf(v[3]);
      ((bf16x4*)outb)[i] = r;
    }
    return;
  }

  // ---- sketch path (validated R0-R13, staged from rt) ----
  const int m0 = blockIdx.x * 64;
  const int tid = threadIdx.x;
  const int w = tid >> 6, l = tid & 63;
  const int lr = l & 15, q = l >> 4;

  f32x4 acc[4][4] = {};

  for (int k0 = 0; k0 < DIM; k0 += 64) {
    #pragma unroll
    for (int i = 0; i < 2; ++i) {
      int v = tid + i * 256;
      int r = v >> 3, vc = v & 7;
      *(bf16x8*)&As[r][vc * 8] = cvt8(x + (size_t)(m0 + r) * DIM + k0 + vc * 8);
    }
    #pragma unroll
    for (int i = 0; i < 8; ++i) {
      int v = tid + i * 256;
      int r = v >> 3, vc = v & 7;
      *(bf16x8*)&Bs[r][vc * 8] = *(const bf16x8*)(rt + (size_t)r * DIM + k0 + vc * 8);
    }
    __syncthreads();
    #pragma unroll
    for (int ks = 0; ks < 2; ++ks) {
      int kk = ks * 32 + q * 8;
      bf16x8 a[4], b[4];
      #pragma unroll
      for (int mi = 0; mi < 4; ++mi) a[mi] = *(bf16x8*)&As[mi * 16 + lr][kk];
      #pragma unroll
      for (int ni = 0; ni < 4; ++ni) b[ni] = *(bf16x8*)&Bs[w * 64 + ni * 16 + lr][kk];
      #pragma unroll
      for (int mi = 0; mi < 4; ++mi)
        #pragma unroll
        for (int ni = 0; ni < 4; ++ni)
          acc[mi][ni] = __builtin_amdgcn_mfma_f32_16x16x32_bf16(a[mi], b[ni], acc[mi][ni], 0, 0, 0);
    }
    __syncthreads();
  }

  float ps[4][4];
  #pragma unroll
  for (int mi = 0; mi < 4; ++mi)
    #pragma unroll
    for (int rg = 0; rg < 4; ++rg) {
      float s = acc[mi][0][rg] * acc[mi][0][rg] + acc[mi][1][rg] * acc[mi][1][rg]
              + acc[mi][2][rg] * acc[mi][2][rg] + acc[mi][3][rg] * acc[mi][3][rg];
      #pragma unroll
      for (int m = 1; m < 16; m <<= 1) s += __shfl_xor(s, m);
      ps[mi][rg] = s;
    }
  if (lr == 0) {
    #pragma unroll
    for (int mi = 0; mi < 4; ++mi)
      #pragma unroll
      for (int rg = 0; rg < 4; ++rg)
        ssum[w][mi * 16 + q * 4 + rg] = ps[mi][rg];
  }
  __syncthreads();

  #pragma unroll
  for (int mi = 0; mi < 4; ++mi)
    #pragma unroll
    for (int rg = 0; rg < 4; ++rg) {
      int r = mi * 16 + q * 4 + rg;
      float tot = ssum[0][r] + ssum[1][r] + ssum[2][r] + ssum[3][r];
      float inv = 1.0f / fmaxf(sqrtf(tot), 1e-12f);
      #pragma unroll
      for (int ni = 0; ni < 4; ++ni) {
        float val = acc[mi][ni][rg] * inv;
        sx[(size_t)(m0 + r) * SKDIM + w * 64 + ni * 16 + lr] = f2bf(val);
      }
    }
}

// K3 v14 (frozen, validated R13): A-in-regs, 16x16x32, 4 LDS slots, counted
// vmcnt window protocol, WR=4. 8 waves (4 wr x 2 wc), block 256 rows x
// (32 n-tiles x 128 cols).
__launch_bounds__(512, 2)
__global__ void gemm_sim(const unsigned short* __restrict__ sx,
                         const unsigned short* __restrict__ bufb,
                         float* __restrict__ partial) {
  __shared__ __align__(16) char lb[65536];

  const int gid = blockIdx.x;
  const int logical = (gid & 7) * 32 + (gid >> 3);
  const int mt = logical & 7;        // 0..7 m-tile (256 rows)
  const int nc = logical >> 3;       // 0..31 n-chunk (4096 cols)
  const int m0 = mt * 256;
  const int ncbase = nc * (NT_PER * 128);

  const int tid = threadIdx.x;
  const int w = tid >> 6, l = tid & 63;
  const int wr = w >> 1, wc = w & 1;        // wave grid 4 x 2
  const int lr = l & 15, q = l >> 4;

  const int scol = ((tid & 7) ^ ((tid >> 4) & 7)) * 8;   // elements
  const int off0 = ((q ^ ((lr >> 1) & 7)) << 4);
  const int off1 = off0 ^ 64;
  const int rowoff = (wc * 64 + lr) * 128;

  bf16x8 areg[4][8];
  {
    const unsigned short* abase = sx + (size_t)(m0 + wr * 64 + lr) * SKDIM + q * 8;
    #pragma unroll
    for (int mi = 0; mi < 4; ++mi)
      #pragma unroll
      for (int kc = 0; kc < 8; ++kc)
        areg[mi][kc] = *(const bf16x8*)(abase + mi * 16 * SKDIM + kc * 32);
  }

  f32x4 acc[4][4] = {};
  float rm[4][4];
  #pragma unroll
  for (int mi = 0; mi < 4; ++mi)
    #pragma unroll
    for (int rg = 0; rg < 4; ++rg) rm[mi][rg] = -3.0e38f;

  bf16x8 bfn[4];

#define STAGE(srcb, kpart, slot_) do {                                         \
    const unsigned short* s0_ = (srcb) + (kpart) * 64;                         \
    char* dst_ = lb + (slot_) * 16384 + tid * 16;                              \
    __builtin_amdgcn_global_load_lds(                                          \
        (const __attribute__((address_space(1))) unsigned int*)s0_,            \
        (__attribute__((address_space(3))) unsigned int*)dst_, 16, 0, 0);      \
    __builtin_amdgcn_global_load_lds(                                          \
        (const __attribute__((address_space(1))) unsigned int*)(s0_ + 64 * SKDIM), \
        (__attribute__((address_space(3))) unsigned int*)(dst_ + 8192), 16, 0, 0); \
  } while (0)

#define RDNEXT(slotN)                                                          \
    _Pragma("unroll")                                                          \
    for (int ni = 0; ni < 4; ++ni)                                             \
      bfn[ni] = *(const bf16x8*)(lb + (slotN) * 16384 + rowoff + ni * 2048 + off0);

#define WINDOW(ks, VM, STAGE_STMT, RDNEXT_STMT) do {                           \
    asm volatile("s_waitcnt vmcnt(" #VM ")" ::: "memory");                     \
    asm volatile("s_barrier" ::: "memory");                                    \
    bf16x8 b1[4];                                                              \
    _Pragma("unroll")                                                          \
    for (int ni = 0; ni < 4; ++ni)                                             \
      b1[ni] = *(const bf16x8*)(lb + (ks) * 16384 + rowoff + ni * 2048 + off1); \
    __builtin_amdgcn_s_setprio(1);                                             \
    _Pragma("unroll")                                                          \
    for (int mi = 0; mi < 4; ++mi)                                             \
      _Pragma("unroll")                                                        \
      for (int ni = 0; ni < 4; ++ni)                                           \
        acc[mi][ni] = __builtin_amdgcn_mfma_f32_16x16x32_bf16(areg[mi][(ks) * 2], bfn[ni], acc[mi][ni], 0, 0, 0); \
    __builtin_amdgcn_s_setprio(0);                                             \
    STAGE_STMT;                                                                \
    __builtin_amdgcn_s_setprio(1);                                             \
    _Pragma("unroll")                                                          \
    for (int mi = 0; mi < 4; ++mi)                                             \
      _Pragma("unroll")                                                        \
      for (int ni = 0; ni < 4; ++ni)                                           \
        acc[mi][ni] = __builtin_amdgcn_mfma_f32_16x16x32_bf16(areg[mi][(ks) * 2 + 1], b1[ni], acc[mi][ni], 0, 0, 0); \
    __builtin_amdgcn_s_setprio(0);                                             \
    RDNEXT_STMT;                                                               \
  } while (0)

#define FOLD do {                                                              \
    _Pragma("unroll")                                                          \
    for (int mi = 0; mi < 4; ++mi)                                             \
      _Pragma("unroll")                                                        \
      for (int rg = 0; rg < 4; ++rg) {                                         \
        float v = fmaxf(fmaxf(acc[mi][0][rg], acc[mi][1][rg]),                 \
                        fmaxf(acc[mi][2][rg], acc[mi][3][rg]));                \
        rm[mi][rg] = fmaxf(rm[mi][rg], v);                                     \
        _Pragma("unroll")                                                      \
        for (int ni = 0; ni < 4; ++ni) acc[mi][ni][rg] = 0.0f;                 \
      }                                                                        \
  } while (0)

  const unsigned short* bsrc = bufb + (size_t)(ncbase + (tid >> 3)) * SKDIM + scol;

  STAGE(bsrc, 0, 0);
  STAGE(bsrc, 1, 1);
  STAGE(bsrc, 2, 2);
  asm volatile("s_waitcnt vmcnt(4)" ::: "memory");
  asm volatile("s_barrier" ::: "memory");
  RDNEXT(0);

  for (int nt = 0; nt < NT_PER - 1; ++nt) {
    const unsigned short* bcur = bsrc;
    bsrc += 128 * SKDIM;
    WINDOW(0, 2, STAGE(bcur, 3, 3), RDNEXT(1));
    WINDOW(1, 2, STAGE(bsrc, 0, 0), RDNEXT(2));
    WINDOW(2, 2, STAGE(bsrc, 1, 1), RDNEXT(3));
    WINDOW(3, 2, STAGE(bsrc, 2, 2), RDNEXT(0));
    FOLD;
  }
  {  // tail n-tile
    const unsigned short* bcur = bsrc;
    WINDOW(0, 2, STAGE(bcur, 3, 3), RDNEXT(1));
    WINDOW(1, 2, (void)0, RDNEXT(2));
    WINDOW(2, 0, (void)0, RDNEXT(3));
    WINDOW(3, 0, (void)0, (void)0);
    FOLD;
  }
#undef STAGE
#undef RDNEXT
#undef WINDOW
#undef FOLD

  #pragma unroll
  for (int mi = 0; mi < 4; ++mi)
    #pragma unroll
    for (int rg = 0; rg < 4; ++rg) {
      float v = rm[mi][rg];
      v = fmaxf(v, __shfl_xor(v, 1));
      v = fmaxf(v, __shfl_xor(v, 2));
      v = fmaxf(v, __shfl_xor(v, 4));
      v = fmaxf(v, __shfl_xor(v, 8));
      rm[mi][rg] = v;
    }

  float* rmaxs = (float*)lb;   // reuse staging LDS: [2 wc][256 rows]
  __syncthreads();
  if (lr == 0) {
    #pragma unroll
    for (int mi = 0; mi < 4; ++mi)
      #pragma unroll
      for (int rg = 0; rg < 4; ++rg)
        rmaxs[wc * 256 + wr * 64 + mi * 16 + q * 4 + rg] = rm[mi][rg];
  }
  __syncthreads();
  if (tid < 256) {
    float v = fmaxf(rmaxs[tid], rmaxs[256 + tid]);
    partial[(size_t)(m0 + tid) * NGROUPS + nc] = v;
  }
}

// K4: out[r] = 1 - max over 32 partials. 2 rows per 64-thread block.
__global__ void reduce_max(const float* __restrict__ partial, float* __restrict__ out) {
  const int r = blockIdx.x * 2 + (threadIdx.x >> 5);
  const int c = threadIdx.x & 31;
  float m = partial[(size_t)r * NGROUPS + c];
  #pragma unroll
  for (int s = 1; s < 32; s <<= 1) m = fmaxf(m, __shfl_xor(m, s));
  if (c == 0) out[r] = 1.0f - m;
}

extern "C" void kernel_launch(void* const* d_in, const int* in_sizes, int n_in,
                              void* d_out, int out_size, void* d_ws, size_t ws_size,
                              hipStream_t stream) {
  const float* x   = (const float*)d_in[0];   // [2048, 2048]
  const float* R   = (const float*)d_in[1];   // [2048, 256]
  const float* buf = (const float*)d_in[2];   // [131072, 256]
  float* out = (float*)d_out;                  // [2048]

  char* ws = (char*)d_ws;
  // ws layout: rt 1MB | buf_bf 64MB | sx_bf 1MB | partial 256KB
  unsigned short* rt   = (unsigned short*)(ws);
  unsigned short* bufb = (unsigned short*)(ws + (1ull << 20));
  unsigned short* sxb  = (unsigned short*)(ws + (1ull << 20) + (64ull << 20));
  float*          part = (float*)         (ws + (1ull << 20) + (64ull << 20) + (1ull << 20));

  transpose_R<<<dim3((DIM * SKDIM) / 256), dim3(256), 0, stream>>>(R, rt);
  sketch_conv<<<dim3(2080), dim3(256), 0, stream>>>(x, rt, sxb, buf, bufb);
  gemm_sim<<<dim3(256), dim3(512), 0, stream>>>(sxb, bufb, part);
  reduce_max<<<dim3(BROWS / 2), dim3(64), 0, stream>>>(part, out);
}